// Round 11
// baseline (295.303 us; speedup 1.0000x reference)
//
#include <hip/hip_runtime.h>
#include <math.h>

#define EPSV 1e-5f
#define SCALE_W 0.0441941738241592f   /* 1/sqrt(512) */
#define GAIN_R 1.4142135623730951f    /* sqrt(2) */

typedef __attribute__((ext_vector_type(8))) short bf16x8;
typedef __attribute__((ext_vector_type(4))) float f32x4;
typedef __attribute__((ext_vector_type(4))) unsigned int u32x4;
typedef __attribute__((ext_vector_type(8))) unsigned short u16x8;

static __device__ __forceinline__ unsigned short f2bf(float f) {
  union { float f; unsigned int u; } v; v.f = f;
  unsigned int r = v.u + 0x7FFFu + ((v.u >> 16) & 1u);   // RNE
  return (unsigned short)(r >> 16);
}

// packed f32->bf16 (RNE), dst.lo=bf16(lo), dst.hi=bf16(hi)
static __device__ __forceinline__ unsigned int cvtpk(float lo, float hi) {
  unsigned int r;
  asm("v_cvt_pk_bf16_f32 %0, %1, %2" : "=v"(r) : "v"(lo), "v"(hi));
  return r;
}

#define GLD_LDS16(gsrc, ldst)                                                                      \
  __builtin_amdgcn_global_load_lds((const __attribute__((address_space(1))) unsigned int*)(gsrc),  \
                                   (__attribute__((address_space(3))) unsigned int*)(ldst), 16, 0, 0)

// ---------------- pre-kernel: b = expmap0(bias), y2 = ||b||^2 ----------------
__global__ void bias_expmap_k(const float* __restrict__ bias, float* __restrict__ bexp,
                              float* __restrict__ y2out) {
  __shared__ float part[8];
  int t = threadIdx.x;
  float bv = bias[t];
  float s = bv * bv;
  s += __shfl_xor(s, 1);  s += __shfl_xor(s, 2);  s += __shfl_xor(s, 4);
  s += __shfl_xor(s, 8);  s += __shfl_xor(s, 16); s += __shfl_xor(s, 32);
  if ((t & 63) == 0) part[t >> 6] = s;
  __syncthreads();
  float tot = 0.f;
#pragma unroll
  for (int i = 0; i < 8; ++i) tot += part[i];
  float un = fmaxf(sqrtf(tot), EPSV);
  float th = tanhf(un);
  bexp[t] = th * bv / un;
  if (t == 0) *y2out = th * th;
}

// ---------------- pre-kernel: pack weight -> bf16 fragments, SCALE baked ----
// chunk = (ks*32 + colhi): 64 lanes x 16B; lane (lgr*16+l15) holds
// W[col=colhi*16+l15][k=ks*32+lgr*8+j], j=0..7.
__global__ void pack_weight_k(const float* __restrict__ w, unsigned short* __restrict__ wsB) {
  int e = blockIdx.x * 256 + threadIdx.x;   // 0..262143
  int o = e >> 9;          // output col (row of W)
  int k = e & 511;
  int ks = k >> 5, kk = k & 31;
  int lgr = kk >> 3, j = kk & 7;
  int colhi = o >> 4, l15 = o & 15;
  int dst = ((ks * 32 + colhi) * 64 + lgr * 16 + l15) * 8 + j;
  wsB[dst] = f2bf(w[e] * SCALE_W);
}

// ---------------- pass 1: m97-style GEMM -> mx(bf16) + xn2, stored in d_out slots ----
// 256 thr / 4 waves (2x2), tile 128x128, BK=32, 16 K-steps.
// d_out row slot r (2048 B): bytes [0,1024) = mx row bf16; byte 1024 = xn2 fp32.
#define P1_ABUF 10240    /* 128 rows x 80 B */
#define P1_BOFF 20480
#define P1_BBUF 8192
#define P1_SMEM 36864

__global__ __launch_bounds__(256, 3)
void gemm_mx_k(const float* __restrict__ x, const unsigned short* __restrict__ wsB,
               float* __restrict__ ob) {
  extern __shared__ char smem[];
  const int tid  = threadIdx.x;
  const int lane = tid & 63;
  const int wave = tid >> 6;
  const int wm = wave >> 1, wn = wave & 1;
  const int l15 = lane & 15, lgr = lane >> 4;
  // XCD-chunked swizzle (4096 = 8*512, bijective): each XCD gets a contiguous m-range
  const int wid = ((blockIdx.x & 7) << 9) + (blockIdx.x >> 3);
  const int tm = wid >> 2, tn = wid & 3;
  const int row_l = tid >> 1;          // staging row 0..127
  const int kh    = tid & 1;           // k-half (16 elems)

  const float* xp = x + (size_t)(tm * 128 + row_l) * 512 + kh * 16;
  char* awr = smem + row_l * 80 + kh * 32;
  const char* ard = smem + (wm * 64 + l15) * 80 + lgr * 16;      // + mf*1280 + buf*P1_ABUF
  const char* brd = smem + P1_BOFF + wn * 4096 + lane * 16;      // + nf*1024 + buf*P1_BBUF

  f32x4 acc[4][4];
#pragma unroll
  for (int mf = 0; mf < 4; ++mf)
#pragma unroll
    for (int nf = 0; nf < 4; ++nf) acc[mf][nf] = f32x4{0.f, 0.f, 0.f, 0.f};

  float xss = 0.f;
  f32x4 st[4];

  // ---- prologue: A(0) -> buf0, issue B(0) ----
  {
#pragma unroll
    for (int i = 0; i < 4; ++i) st[i] = *(const f32x4*)(xp + i * 4);
    u32x4 pa, pb;
#pragma unroll
    for (int i = 0; i < 4; ++i) {
      f32x4 v = st[i];
      xss += v[0]*v[0] + v[1]*v[1] + v[2]*v[2] + v[3]*v[3];
    }
    pa[0] = cvtpk(st[0][0], st[0][1]); pa[1] = cvtpk(st[0][2], st[0][3]);
    pa[2] = cvtpk(st[1][0], st[1][1]); pa[3] = cvtpk(st[1][2], st[1][3]);
    pb[0] = cvtpk(st[2][0], st[2][1]); pb[1] = cvtpk(st[2][2], st[2][3]);
    pb[2] = cvtpk(st[3][0], st[3][1]); pb[3] = cvtpk(st[3][2], st[3][3]);
    *(u32x4*)(awr) = pa;
    *(u32x4*)(awr + 16) = pb;
    const char* bs = (const char*)wsB + tn * 8192;
    GLD_LDS16(bs + tid * 16, smem + P1_BOFF + tid * 16);
    GLD_LDS16(bs + 4096 + tid * 16, smem + P1_BOFF + 4096 + tid * 16);
  }
  __syncthreads();

#pragma unroll 1
  for (int t = 0; t < 16; ++t) {
    const int cur = t & 1, nxt = cur ^ 1;
    if (t < 15) {
      // issue B(t+1) -> buf nxt
      const char* bs = (const char*)wsB + (size_t)(t + 1) * 32768 + tn * 8192;
      char* bd = smem + P1_BOFF + nxt * P1_BBUF;
      GLD_LDS16(bs + tid * 16, bd + tid * 16);
      GLD_LDS16(bs + 4096 + tid * 16, bd + 4096 + tid * 16);
      // load A(t+1) regs
      const float* p = xp + (t + 1) * 32;
#pragma unroll
      for (int i = 0; i < 4; ++i) st[i] = *(const f32x4*)(p + i * 4);
    }
    // fragments + MFMA on buf cur
    {
      bf16x8 xf[4], wf[4];
#pragma unroll
      for (int mf = 0; mf < 4; ++mf)
        xf[mf] = *(const bf16x8*)(ard + cur * P1_ABUF + mf * 1280);
#pragma unroll
      for (int nf = 0; nf < 4; ++nf)
        wf[nf] = *(const bf16x8*)(brd + cur * P1_BBUF + nf * 1024);
#pragma unroll
      for (int mf = 0; mf < 4; ++mf)
#pragma unroll
        for (int nf = 0; nf < 4; ++nf)
          acc[mf][nf] = __builtin_amdgcn_mfma_f32_16x16x32_bf16(wf[nf], xf[mf], acc[mf][nf], 0, 0, 0);
    }
    __syncthreads();   // drains A-loads + gloads (m97 pattern)
    if (t < 15) {
      u32x4 pa, pb;
#pragma unroll
      for (int i = 0; i < 4; ++i) {
        f32x4 v = st[i];
        xss += v[0]*v[0] + v[1]*v[1] + v[2]*v[2] + v[3]*v[3];
      }
      pa[0] = cvtpk(st[0][0], st[0][1]); pa[1] = cvtpk(st[0][2], st[0][3]);
      pa[2] = cvtpk(st[1][0], st[1][1]); pa[3] = cvtpk(st[1][2], st[1][3]);
      pb[0] = cvtpk(st[2][0], st[2][1]); pb[1] = cvtpk(st[2][2], st[2][3]);
      pb[2] = cvtpk(st[3][0], st[3][1]); pb[3] = cvtpk(st[3][2], st[3][3]);
      char* aw = awr + nxt * P1_ABUF;
      *(u32x4*)(aw) = pa;
      *(u32x4*)(aw + 16) = pb;
    }
    __syncthreads();
  }

  // ---- epilogue: mx (bf16) into row slots; xn2 at float offset 256 ----
  unsigned short* mxu = (unsigned short*)ob;
  const long rowb = (long)tm * 128 + wm * 64;
  const int colb = tn * 128 + wn * 64;
#pragma unroll
  for (int mf = 0; mf < 4; ++mf)
#pragma unroll
    for (int nf = 0; nf < 4; ++nf) {
      uint2 pk;
      pk.x = cvtpk(acc[mf][nf][0], acc[mf][nf][1]);
      pk.y = cvtpk(acc[mf][nf][2], acc[mf][nf][3]);
      *(uint2*)(mxu + (size_t)(rowb + mf * 16 + l15) * 1024 + colb + nf * 16 + lgr * 4) = pk;
    }
  float xs = xss + __shfl_xor(xss, 1);   // pair covers full row
  if (tn == 0 && kh == 0)
    ob[(size_t)(tm * 128 + row_l) * 512 + 256] = xs;
}

// ---------------- pass 2: hyperbolic epilogue, one wave per row ----------------
#define BFLY(v) { v += __shfl_xor(v, 1); v += __shfl_xor(v, 2); v += __shfl_xor(v, 4); \
                  v += __shfl_xor(v, 8); v += __shfl_xor(v, 16); v += __shfl_xor(v, 32); }

__global__ __launch_bounds__(256, 8)
void hyp_epi_k(float* __restrict__ ob, const float* __restrict__ bexp,
               const float* __restrict__ y2p) {
  const int lane = threadIdx.x & 63;
  const int wave = threadIdx.x >> 6;
  const long rbase = (long)blockIdx.x * 64;
  // per-lane bias fragment (cols lane*8..lane*8+7), hoisted
  f32x4 be0 = *(const f32x4*)(bexp + lane * 8);
  f32x4 be1 = *(const f32x4*)(bexp + lane * 8 + 4);
  const float y2v = *y2p;

#pragma unroll 1
  for (int it = 0; it < 8; ++it) {
    const long r0 = rbase + it * 8 + wave * 2;
    // ---- load both rows up front (ILP) ----
    const u16x8 m0 = *(const u16x8*)((const unsigned short*)ob + r0 * 1024 + lane * 8);
    const u16x8 m1 = *(const u16x8*)((const unsigned short*)ob + (r0 + 1) * 1024 + lane * 8);
    const float xq0 = ob[r0 * 512 + 256];
    const float xq1 = ob[(r0 + 1) * 512 + 256];

    float a0[8], a1[8];
#pragma unroll
    for (int j = 0; j < 8; ++j) {
      union { unsigned int u; float f; } c0, c1;
      c0.u = ((unsigned int)(unsigned short)m0[j]) << 16;
      c1.u = ((unsigned int)(unsigned short)m1[j]) << 16;
      a0[j] = c0.f; a1[j] = c1.f;
    }
    float bv[8] = {be0[0], be0[1], be0[2], be0[3], be1[0], be1[1], be1[2], be1[3]};

    float s20 = 0.f, sb0 = 0.f, s21 = 0.f, sb1 = 0.f;
#pragma unroll
    for (int j = 0; j < 8; ++j) {
      s20 += a0[j] * a0[j];  sb0 += a0[j] * bv[j];
      s21 += a1[j] * a1[j];  sb1 += a1[j] * bv[j];
    }
    BFLY(s20); BFLY(sb0); BFLY(s21); BFLY(sb1);

    // per-row scalars (redundant across lanes)
    float g1a, g2a, g1b, g2b;
    {
      float xn  = fmaxf(sqrtf(xq0), EPSV);
      float mxn = fmaxf(sqrtf(s20), EPSV);
      float f = tanhf((mxn / xn) * atanhf(fminf(xn, 1.f - EPSV))) / mxn;
      float xy = f * sb0, x2 = f * f * s20;
      float den = 1.f + 2.f * xy + x2 * y2v + EPSV;
      g1a = (1.f + 2.f * xy + y2v) * f / den;
      g2a = (1.f - x2) / den;
      float n1sq = g1a * g1a * s20 + 2.f * g1a * g2a * sb0 + g2a * g2a * y2v;
      float n1 = fmaxf(sqrtf(fmaxf(n1sq, 0.f)), EPSV);
      if (n1 > 0.999f) { float sc = 0.999f / n1; g1a *= sc; g2a *= sc; }
    }
    {
      float xn  = fmaxf(sqrtf(xq1), EPSV);
      float mxn = fmaxf(sqrtf(s21), EPSV);
      float f = tanhf((mxn / xn) * atanhf(fminf(xn, 1.f - EPSV))) / mxn;
      float xy = f * sb1, x2 = f * f * s21;
      float den = 1.f + 2.f * xy + x2 * y2v + EPSV;
      g1b = (1.f + 2.f * xy + y2v) * f / den;
      g2b = (1.f - x2) / den;
      float n1sq = g1b * g1b * s21 + 2.f * g1b * g2b * sb1 + g2b * g2b * y2v;
      float n1 = fmaxf(sqrtf(fmaxf(n1sq, 0.f)), EPSV);
      if (n1 > 0.999f) { float sc = 0.999f / n1; g1b *= sc; g2b *= sc; }
    }

    // v = lrelu(g1*mx + g2*b), ||v||, mobius scalar mult, store
    float v0[8], v1[8], n20 = 0.f, n21 = 0.f;
#pragma unroll
    for (int j = 0; j < 8; ++j) {
      float u0 = g1a * a0[j] + g2a * bv[j];
      float u1 = g1b * a1[j] + g2b * bv[j];
      u0 = u0 > 0.f ? u0 : 0.2f * u0;
      u1 = u1 > 0.f ? u1 : 0.2f * u1;
      v0[j] = u0; v1[j] = u1;
      n20 += u0 * u0; n21 += u1 * u1;
    }
    BFLY(n20); BFLY(n21);
    float nn0 = fmaxf(sqrtf(n20), EPSV);
    float nn1 = fmaxf(sqrtf(n21), EPSV);
    float tm0 = tanhf(GAIN_R * atanhf(fminf(nn0, 1.f - EPSV))) / nn0;
    float tm1 = tanhf(GAIN_R * atanhf(fminf(nn1, 1.f - EPSV))) / nn1;

    f32x4 o00 = {tm0 * v0[0], tm0 * v0[1], tm0 * v0[2], tm0 * v0[3]};
    f32x4 o01 = {tm0 * v0[4], tm0 * v0[5], tm0 * v0[6], tm0 * v0[7]};
    f32x4 o10 = {tm1 * v1[0], tm1 * v1[1], tm1 * v1[2], tm1 * v1[3]};
    f32x4 o11 = {tm1 * v1[4], tm1 * v1[5], tm1 * v1[6], tm1 * v1[7]};
    *(f32x4*)(ob + r0 * 512 + lane * 8)           = o00;
    *(f32x4*)(ob + r0 * 512 + lane * 8 + 4)       = o01;
    *(f32x4*)(ob + (r0 + 1) * 512 + lane * 8)     = o10;
    *(f32x4*)(ob + (r0 + 1) * 512 + lane * 8 + 4) = o11;
  }
}

extern "C" void kernel_launch(void* const* d_in, const int* in_sizes, int n_in,
                              void* d_out, int out_size, void* d_ws, size_t ws_size,
                              hipStream_t stream) {
  const float* x    = (const float*)d_in[0];
  const float* w    = (const float*)d_in[1];
  const float* bias = (const float*)d_in[2];
  float* out = (float*)d_out;

  unsigned short* wsB = (unsigned short*)d_ws;                 // 524288 B
  float* bexp = (float*)((char*)d_ws + 524288);                // 2048 B
  float* y2p  = (float*)((char*)d_ws + 524288 + 2048);         // 4 B

  bias_expmap_k<<<dim3(1), dim3(512), 0, stream>>>(bias, bexp, y2p);
  pack_weight_k<<<dim3(1024), dim3(256), 0, stream>>>(w, wsB);

  // pass 1: GEMM -> mx bf16 + xn2 staged inside d_out row slots
  gemm_mx_k<<<dim3(4096), dim3(256), P1_SMEM, stream>>>(x, wsB, out);
  // pass 2: hyperbolic epilogue, in-place per row
  hyp_epi_k<<<dim3(2048), dim3(256), 0, stream>>>(out, bexp, y2p);
}